// Round 1
// baseline (838.305 us; speedup 1.0000x reference)
//
#include <hip/hip_runtime.h>
#include <hip/hip_bf16.h>

// RoIAlign (FPN, 4 levels) + SR=2x2 sample-mean + 2x2 stride-1 avg pool.
// B=2, N=512 rois, C=256, PH=PW=7, output (B*N, C*6*6) fp32.
// One block per ROI; thread t = channel t. Sample geometry precomputed in LDS.

#define PH 7
#define SR 2
#define C_CH 256
#define N_ROI 512
#define B_BATCH 2
#define H0 160

__global__ __launch_bounds__(256) void roialign_kernel(
    const float* __restrict__ f0, const float* __restrict__ f1,
    const float* __restrict__ f2, const float* __restrict__ f3,
    const float* __restrict__ rois, float* __restrict__ out)
{
    const int roi = blockIdx.x;            // 0 .. B*N-1
    const int b   = roi / N_ROI;
    const float* r = rois + (size_t)roi * 7;

    // Per-axis sample records (14 samples each axis)
    __shared__ int   s_y0[14], s_y1[14], s_x0[14], s_x1[14];
    __shared__ float s_ly[14], s_lx[14], s_vy[14], s_vx[14];

    // Level-uniform per block
    const int lev = (int)r[6];
    int H;
    const float* f;
    if      (lev == 0) { H = 160; f = f0; }
    else if (lev == 1) { H = 80;  f = f1; }
    else if (lev == 2) { H = 40;  f = f2; }
    else               { H = 20;  f = f3; }
    const int W = H;
    const float scale = (8.0f * (float)H) / (float)H0;   // sw == sh (square maps)

    const float x1 = r[1] * scale, y1 = r[2] * scale;
    const float x2 = r[3] * scale, y2 = r[4] * scale;
    const float rw = fmaxf(x2 - x1, 1.0f);
    const float rh = fmaxf(y2 - y1, 1.0f);
    const float bw = rw * (1.0f / (float)PH);
    const float bh = rh * (1.0f / (float)PH);

    const int t = threadIdx.x;
    if (t < 14) {
        // y-axis sample t
        const float off = (float)(t >> 1) + 0.25f + 0.5f * (float)(t & 1);
        const float ys  = y1 + off * bh;
        s_vy[t] = (ys >= -1.0f && ys <= (float)H) ? 1.0f : 0.0f;
        const float y  = fminf(fmaxf(ys, 0.0f), (float)(H - 1));
        const float yf = floorf(y);
        s_ly[t] = y - yf;
        const int y0 = (int)yf;
        s_y0[t] = y0;
        s_y1[t] = min(y0 + 1, H - 1);
    } else if (t < 28) {
        // x-axis sample t-14
        const int k = t - 14;
        const float off = (float)(k >> 1) + 0.25f + 0.5f * (float)(k & 1);
        const float xs  = x1 + off * bw;
        s_vx[k] = (xs >= -1.0f && xs <= (float)W) ? 1.0f : 0.0f;
        const float x  = fminf(fmaxf(xs, 0.0f), (float)(W - 1));
        const float xf = floorf(x);
        s_lx[k] = x - xf;
        const int x0 = (int)xf;
        s_x0[k] = x0;
        s_x1[k] = min(x0 + 1, W - 1);
    }
    __syncthreads();

    const int c = t;  // one channel per thread
    const float* __restrict__ fc = f + ((size_t)b * C_CH + c) * (size_t)(H * W);
    float* __restrict__ o_base = out + (size_t)roi * (C_CH * 36) + (size_t)c * 36;

    float prev[PH];   // previous pooled bin row (7 wide)

    for (int i = 0; i < PH; ++i) {
        // y-sample pair for this bin row
        const int   sy0 = 2 * i, sy1 = 2 * i + 1;
        const int   ya0 = s_y0[sy0], ya1 = s_y1[sy0];
        const int   yb0 = s_y0[sy1], yb1 = s_y1[sy1];
        const float lya = s_ly[sy0], vya = s_vy[sy0];
        const float lyb = s_ly[sy1], vyb = s_vy[sy1];
        const float* __restrict__ ra0 = fc + ya0 * W;
        const float* __restrict__ ra1 = fc + ya1 * W;
        const float* __restrict__ rb0 = fc + yb0 * W;
        const float* __restrict__ rb1 = fc + yb1 * W;

        float cur[PH];
        #pragma unroll
        for (int j = 0; j < PH; ++j) {
            float acc = 0.0f;
            #pragma unroll
            for (int sj = 0; sj < 2; ++sj) {
                const int   sx  = 2 * j + sj;
                const int   x0  = s_x0[sx], x1i = s_x1[sx];
                const float lx  = s_lx[sx], vx  = s_vx[sx];
                // sample at (sy0, sx)
                {
                    const float f00 = ra0[x0],  f01 = ra0[x1i];
                    const float f10 = ra1[x0],  f11 = ra1[x1i];
                    const float top = f00 + lx * (f01 - f00);
                    const float bot = f10 + lx * (f11 - f10);
                    acc += (vya * vx) * (top + lya * (bot - top));
                }
                // sample at (sy1, sx)
                {
                    const float f00 = rb0[x0],  f01 = rb0[x1i];
                    const float f10 = rb1[x0],  f11 = rb1[x1i];
                    const float top = f00 + lx * (f01 - f00);
                    const float bot = f10 + lx * (f11 - f10);
                    acc += (vyb * vx) * (top + lyb * (bot - top));
                }
            }
            cur[j] = acc * 0.25f;   // mean over the 2x2 samples
        }

        if (i > 0) {
            // emit output row i-1 of the 6x6 stride-1 2x2 avg pool
            float* __restrict__ o = o_base + (size_t)(i - 1) * 6;
            #pragma unroll
            for (int j = 0; j < 6; ++j)
                o[j] = 0.25f * (prev[j] + prev[j + 1] + cur[j] + cur[j + 1]);
        }
        #pragma unroll
        for (int j = 0; j < PH; ++j) prev[j] = cur[j];
    }
}

extern "C" void kernel_launch(void* const* d_in, const int* in_sizes, int n_in,
                              void* d_out, int out_size, void* d_ws, size_t ws_size,
                              hipStream_t stream) {
    const float* f0   = (const float*)d_in[0];
    const float* f1   = (const float*)d_in[1];
    const float* f2   = (const float*)d_in[2];
    const float* f3   = (const float*)d_in[3];
    const float* rois = (const float*)d_in[4];
    float* out = (float*)d_out;

    const int n_rois = in_sizes[4] / 7;   // B*N = 1024
    roialign_kernel<<<n_rois, 256, 0, stream>>>(f0, f1, f2, f3, rois, out);
}

// Round 2
// 205.126 us; speedup vs baseline: 4.0868x; 4.0868x over previous
//
#include <hip/hip_runtime.h>
#include <hip/hip_bf16.h>

// RoIAlign (FPN, 4 levels) + SR=2x2 sample-mean + 2x2 stride-1 avg pool.
// B=2, N=512 rois, C=256, PH=PW=7, output (B*N, C*6*6) fp32.
//
// Round 2: channels-last pre-transpose into d_ws so every bilinear tap is a
// coalesced wave read of 64 consecutive floats (was: 64 distinct cache lines
// per tap -> 1.58 GB FETCH_SIZE). Output staged in padded LDS and written
// coalesced. Falls back to the direct-layout path if ws_size is too small.

#define PH 7
#define C_CH 256
#define N_ROI 512
#define H0 160

// level sizes (P = H*W)
#define P0 25600
#define P1 6400
#define P2 1600
#define P3 400
// float offsets into ws for each transposed level (B=2, C=256)
#define OFF0 0ull
#define OFF1 (OFF0 + 2ull * C_CH * P0)
#define OFF2 (OFF1 + 2ull * C_CH * P1)
#define OFF3 (OFF2 + 2ull * C_CH * P2)
#define WS_FLOATS (OFF3 + 2ull * C_CH * P3)   // 17,408,000 floats = 69,632,000 B

// ---------------- (B,C,P) -> (B,P,C) tiled transpose ----------------
__global__ __launch_bounds__(256) void transpose_kernel(
    const float* __restrict__ in, float* __restrict__ T, int P)
{
    __shared__ float tile[64][65];
    const int p0 = blockIdx.x * 64;
    const int c0 = blockIdx.y * 64;
    const int b  = blockIdx.z;
    const int t  = threadIdx.x;
    const int lx = t & 63;
    const int r0 = t >> 6;           // 0..3

    const float* A = in + ((size_t)b * C_CH + c0) * (size_t)P + p0;
    if (p0 + lx < P) {
        #pragma unroll
        for (int k = 0; k < 16; ++k) {
            const int cc = r0 + k * 4;
            tile[cc][lx] = A[(size_t)cc * P + lx];   // coalesced along P
        }
    }
    __syncthreads();
    float* To = T + ((size_t)b * P + p0) * C_CH + c0 + lx;
    #pragma unroll
    for (int k = 0; k < 16; ++k) {
        const int pp = r0 + k * 4;
        if (p0 + pp < P)
            To[(size_t)pp * C_CH] = tile[lx][pp];    // coalesced along C
    }
}

// ---------------- main gather kernel ----------------
__global__ __launch_bounds__(256) void roialign_kernel(
    const float* __restrict__ f0, const float* __restrict__ f1,
    const float* __restrict__ f2, const float* __restrict__ f3,
    const float* __restrict__ t0, const float* __restrict__ t1,
    const float* __restrict__ t2, const float* __restrict__ t3,
    const float* __restrict__ rois, float* __restrict__ out, int use_t)
{
    const int roi = blockIdx.x;            // 0 .. B*N-1
    const int b   = roi / N_ROI;
    const float* r = rois + (size_t)roi * 7;

    // Per-axis sample records (offsets pre-scaled by memory strides)
    __shared__ int   s_y0[14], s_y1[14], s_x0[14], s_x1[14];
    __shared__ float s_ly[14], s_lx[14], s_vy[14], s_vx[14];
    __shared__ float s_out[C_CH * 37];     // 36 vals/channel, +1 pad for banks

    const int lev = (int)r[6];
    int H; const float* fd; const float* ft;
    if      (lev == 0) { H = 160; fd = f0; ft = t0; }
    else if (lev == 1) { H = 80;  fd = f1; ft = t1; }
    else if (lev == 2) { H = 40;  fd = f2; ft = t2; }
    else               { H = 20;  fd = f3; ft = t3; }
    const int W = H;
    const int P = H * W;
    const int xstr = use_t ? C_CH : 1;         // element stride along x
    const int rstr = use_t ? W * C_CH : W;     // element stride along y

    const float scale = (8.0f * (float)H) / (float)H0;
    const float x1 = r[1] * scale, y1 = r[2] * scale;
    const float x2 = r[3] * scale, y2 = r[4] * scale;
    const float bw = fmaxf(x2 - x1, 1.0f) * (1.0f / (float)PH);
    const float bh = fmaxf(y2 - y1, 1.0f) * (1.0f / (float)PH);

    const int t = threadIdx.x;
    if (t < 14) {
        const float off = (float)(t >> 1) + 0.25f + 0.5f * (float)(t & 1);
        const float ys  = y1 + off * bh;
        s_vy[t] = (ys >= -1.0f && ys <= (float)H) ? 1.0f : 0.0f;
        const float y  = fminf(fmaxf(ys, 0.0f), (float)(H - 1));
        const float yf = floorf(y);
        s_ly[t] = y - yf;
        const int y0 = (int)yf;
        s_y0[t] = y0 * rstr;
        s_y1[t] = min(y0 + 1, H - 1) * rstr;
    } else if (t < 28) {
        const int k = t - 14;
        const float off = (float)(k >> 1) + 0.25f + 0.5f * (float)(k & 1);
        const float xs  = x1 + off * bw;
        s_vx[k] = (xs >= -1.0f && xs <= (float)W) ? 1.0f : 0.0f;
        const float x  = fminf(fmaxf(xs, 0.0f), (float)(W - 1));
        const float xf = floorf(x);
        s_lx[k] = x - xf;
        const int x0 = (int)xf;
        s_x0[k] = x0 * xstr;
        s_x1[k] = min(x0 + 1, W - 1) * xstr;
    }
    __syncthreads();

    const int c = t;  // one channel per thread
    const float* __restrict__ cbase = use_t
        ? (ft + (size_t)b * P * C_CH + c)
        : (fd + ((size_t)b * C_CH + c) * (size_t)P);
    float* __restrict__ sOut = s_out + c * 37;

    float prev[PH];

    for (int i = 0; i < PH; ++i) {
        const int   sy0 = 2 * i, sy1 = 2 * i + 1;
        const float lya = s_ly[sy0], vya = s_vy[sy0];
        const float lyb = s_ly[sy1], vyb = s_vy[sy1];
        const float* __restrict__ ra0 = cbase + s_y0[sy0];
        const float* __restrict__ ra1 = cbase + s_y1[sy0];
        const float* __restrict__ rb0 = cbase + s_y0[sy1];
        const float* __restrict__ rb1 = cbase + s_y1[sy1];

        float cur[PH];
        #pragma unroll
        for (int j = 0; j < PH; ++j) {
            float acc = 0.0f;
            #pragma unroll
            for (int sj = 0; sj < 2; ++sj) {
                const int   sx  = 2 * j + sj;
                const int   x0  = s_x0[sx], x1i = s_x1[sx];
                const float lx  = s_lx[sx], vx  = s_vx[sx];
                {
                    const float f00 = ra0[x0],  f01 = ra0[x1i];
                    const float f10 = ra1[x0],  f11 = ra1[x1i];
                    const float top = f00 + lx * (f01 - f00);
                    const float bot = f10 + lx * (f11 - f10);
                    acc += (vya * vx) * (top + lya * (bot - top));
                }
                {
                    const float f00 = rb0[x0],  f01 = rb0[x1i];
                    const float f10 = rb1[x0],  f11 = rb1[x1i];
                    const float top = f00 + lx * (f01 - f00);
                    const float bot = f10 + lx * (f11 - f10);
                    acc += (vyb * vx) * (top + lyb * (bot - top));
                }
            }
            cur[j] = acc * 0.25f;
        }

        if (i > 0) {
            float* __restrict__ o = sOut + (i - 1) * 6;
            #pragma unroll
            for (int j = 0; j < 6; ++j)
                o[j] = 0.25f * (prev[j] + prev[j + 1] + cur[j] + cur[j + 1]);
        }
        #pragma unroll
        for (int j = 0; j < PH; ++j) prev[j] = cur[j];
    }

    __syncthreads();
    // coalesced store of the ROI's 9216 outputs
    float* __restrict__ orow = out + (size_t)roi * (C_CH * 36);
    #pragma unroll
    for (int e = t; e < C_CH * 36; e += 256) {
        const int cc = e / 36;
        const int kk = e - 36 * cc;
        orow[e] = s_out[cc * 37 + kk];
    }
}

extern "C" void kernel_launch(void* const* d_in, const int* in_sizes, int n_in,
                              void* d_out, int out_size, void* d_ws, size_t ws_size,
                              hipStream_t stream) {
    const float* f0   = (const float*)d_in[0];
    const float* f1   = (const float*)d_in[1];
    const float* f2   = (const float*)d_in[2];
    const float* f3   = (const float*)d_in[3];
    const float* rois = (const float*)d_in[4];
    float* out = (float*)d_out;
    float* ws  = (float*)d_ws;

    const int n_rois = in_sizes[4] / 7;   // B*N = 1024
    const size_t need = WS_FLOATS * sizeof(float);
    const int use_t = (ws != nullptr && ws_size >= need) ? 1 : 0;

    const float* t0 = f0; const float* t1 = f1;
    const float* t2 = f2; const float* t3 = f3;
    if (use_t) {
        float* T0 = ws + OFF0;
        float* T1 = ws + OFF1;
        float* T2 = ws + OFF2;
        float* T3 = ws + OFF3;
        transpose_kernel<<<dim3((P0 + 63) / 64, 4, 2), 256, 0, stream>>>(f0, T0, P0);
        transpose_kernel<<<dim3((P1 + 63) / 64, 4, 2), 256, 0, stream>>>(f1, T1, P1);
        transpose_kernel<<<dim3((P2 + 63) / 64, 4, 2), 256, 0, stream>>>(f2, T2, P2);
        transpose_kernel<<<dim3((P3 + 63) / 64, 4, 2), 256, 0, stream>>>(f3, T3, P3);
        t0 = T0; t1 = T1; t2 = T2; t3 = T3;
    }

    roialign_kernel<<<n_rois, 256, 0, stream>>>(
        f0, f1, f2, f3, t0, t1, t2, t3, rois, out, use_t);
}

// Round 3
// 166.030 us; speedup vs baseline: 5.0491x; 1.2355x over previous
//
#include <hip/hip_runtime.h>
#include <hip/hip_bf16.h>
#include <hip/hip_fp16.h>

// RoIAlign (FPN, 4 levels) + SR=2x2 sample-mean + 2x2 stride-1 avg pool.
// B=2, N=512 rois, C=256, PH=PW=7, output (B*N, C*6*6) fp32.
//
// Round 3: transposed features stored as fp16 channels-last (halves gather
// line traffic, working set 33 MB ~ L2), all 4 level transposes fused into
// one launch. Gather taps: 64 lanes x 2B = one 128B line per wave.

#define PH 7
#define C_CH 256
#define N_ROI 512
#define H0 160

// level sizes (P = H*W)
#define P0 25600
#define P1 6400
#define P2 1600
#define P3 400
// half-element offsets into ws for each transposed level (B=2, C=256)
#define OFF0 0ull
#define OFF1 (OFF0 + 2ull * C_CH * P0)
#define OFF2 (OFF1 + 2ull * C_CH * P1)
#define OFF3 (OFF2 + 2ull * C_CH * P2)
#define WS_HALFS (OFF3 + 2ull * C_CH * P3)   // 17,408,000 halves = 34.8 MB

// tile counts per level: tiles_p * 4 (c-tiles) * 2 (batch)
#define NB0 (400 * 8)          // 3200
#define NB1 (100 * 8)          // 800
#define NB2 (25 * 8)           // 200
#define NB3 (7 * 8)            // 56  (448 > 400 -> bounds-checked)
#define NB_ALL (NB0 + NB1 + NB2 + NB3)

// ------------- fused (B,C,P) -> (B,P,C) transpose, fp32 -> fp16 -------------
__global__ __launch_bounds__(256) void transpose_f16_kernel(
    const float* __restrict__ f0, const float* __restrict__ f1,
    const float* __restrict__ f2, const float* __restrict__ f3,
    __half* __restrict__ ws)
{
    __shared__ float tile[64][65];
    int bid = blockIdx.x;
    const float* in; __half* out; int P;
    if (bid < NB0)                  {              in = f0; out = ws + OFF0; P = P0; }
    else if (bid < NB0 + NB1)       { bid -= NB0;  in = f1; out = ws + OFF1; P = P1; }
    else if (bid < NB0 + NB1 + NB2) { bid -= NB0 + NB1; in = f2; out = ws + OFF2; P = P2; }
    else                            { bid -= NB0 + NB1 + NB2; in = f3; out = ws + OFF3; P = P3; }
    const int tiles_p = (P + 63) >> 6;
    const int tp   = bid % tiles_p;
    const int rest = bid / tiles_p;
    const int c0 = (rest & 3) << 6;
    const int b  = rest >> 2;
    const int p0 = tp << 6;

    const int t  = threadIdx.x;
    const int lx = t & 63;
    const int r0 = t >> 6;          // 0..3

    const float* A = in + ((size_t)b * C_CH + c0) * (size_t)P + p0;
    if (p0 + lx < P) {
        #pragma unroll
        for (int k = 0; k < 16; ++k) {
            const int cc = r0 + k * 4;
            tile[cc][lx] = A[(size_t)cc * P + lx];     // coalesced along P
        }
    }
    __syncthreads();
    __half* To = out + ((size_t)b * P + p0) * C_CH + c0 + lx;
    #pragma unroll
    for (int k = 0; k < 16; ++k) {
        const int pp = r0 + k * 4;
        if (p0 + pp < P)
            To[(size_t)pp * C_CH] = __float2half(tile[lx][pp]);  // coalesced along C
    }
}

// ---------------- main gather kernel (fp16 channels-last) ----------------
__global__ __launch_bounds__(256) void roialign_kernel(
    const __half* __restrict__ ws,
    const float* __restrict__ rois, float* __restrict__ out)
{
    const int roi = blockIdx.x;            // 0 .. B*N-1
    const int b   = roi / N_ROI;
    const float* r = rois + (size_t)roi * 7;

    __shared__ int   s_y0[14], s_y1[14], s_x0[14], s_x1[14];
    __shared__ float s_ly[14], s_lx[14], s_vy[14], s_vx[14];
    __shared__ float s_out[C_CH * 37];     // 36 vals/channel, +1 pad

    const int lev = (int)r[6];
    int H; const __half* ft;
    if      (lev == 0) { H = 160; ft = ws + OFF0; }
    else if (lev == 1) { H = 80;  ft = ws + OFF1; }
    else if (lev == 2) { H = 40;  ft = ws + OFF2; }
    else               { H = 20;  ft = ws + OFF3; }
    const int W = H;
    const int P = H * W;

    const float scale = (8.0f * (float)H) / (float)H0;
    const float x1 = r[1] * scale, y1 = r[2] * scale;
    const float x2 = r[3] * scale, y2 = r[4] * scale;
    const float bw = fmaxf(x2 - x1, 1.0f) * (1.0f / (float)PH);
    const float bh = fmaxf(y2 - y1, 1.0f) * (1.0f / (float)PH);

    const int t = threadIdx.x;
    if (t < 14) {
        const float off = (float)(t >> 1) + 0.25f + 0.5f * (float)(t & 1);
        const float ys  = y1 + off * bh;
        s_vy[t] = (ys >= -1.0f && ys <= (float)H) ? 1.0f : 0.0f;
        const float y  = fminf(fmaxf(ys, 0.0f), (float)(H - 1));
        const float yf = floorf(y);
        s_ly[t] = y - yf;
        const int y0 = (int)yf;
        s_y0[t] = y0 * (W * C_CH);
        s_y1[t] = min(y0 + 1, H - 1) * (W * C_CH);
    } else if (t < 28) {
        const int k = t - 14;
        const float off = (float)(k >> 1) + 0.25f + 0.5f * (float)(k & 1);
        const float xs  = x1 + off * bw;
        s_vx[k] = (xs >= -1.0f && xs <= (float)W) ? 1.0f : 0.0f;
        const float x  = fminf(fmaxf(xs, 0.0f), (float)(W - 1));
        const float xf = floorf(x);
        s_lx[k] = x - xf;
        const int x0 = (int)xf;
        s_x0[k] = x0 * C_CH;
        s_x1[k] = min(x0 + 1, W - 1) * C_CH;
    }
    __syncthreads();

    const int c = t;  // one channel per thread
    const __half* __restrict__ cbase = ft + (size_t)b * P * C_CH + c;
    float* __restrict__ sOut = s_out + c * 37;

    float prev[PH];

    for (int i = 0; i < PH; ++i) {
        const int   sy0 = 2 * i, sy1 = 2 * i + 1;
        const float lya = s_ly[sy0], vya = s_vy[sy0];
        const float lyb = s_ly[sy1], vyb = s_vy[sy1];
        const __half* __restrict__ ra0 = cbase + s_y0[sy0];
        const __half* __restrict__ ra1 = cbase + s_y1[sy0];
        const __half* __restrict__ rb0 = cbase + s_y0[sy1];
        const __half* __restrict__ rb1 = cbase + s_y1[sy1];

        float cur[PH];
        #pragma unroll
        for (int j = 0; j < PH; ++j) {
            float acc = 0.0f;
            #pragma unroll
            for (int sj = 0; sj < 2; ++sj) {
                const int   sx  = 2 * j + sj;
                const int   x0  = s_x0[sx], x1i = s_x1[sx];
                const float lx  = s_lx[sx], vx  = s_vx[sx];
                {
                    const float f00 = __half2float(ra0[x0]);
                    const float f01 = __half2float(ra0[x1i]);
                    const float f10 = __half2float(ra1[x0]);
                    const float f11 = __half2float(ra1[x1i]);
                    const float top = f00 + lx * (f01 - f00);
                    const float bot = f10 + lx * (f11 - f10);
                    acc += (vya * vx) * (top + lya * (bot - top));
                }
                {
                    const float f00 = __half2float(rb0[x0]);
                    const float f01 = __half2float(rb0[x1i]);
                    const float f10 = __half2float(rb1[x0]);
                    const float f11 = __half2float(rb1[x1i]);
                    const float top = f00 + lx * (f01 - f00);
                    const float bot = f10 + lx * (f11 - f10);
                    acc += (vyb * vx) * (top + lyb * (bot - top));
                }
            }
            cur[j] = acc * 0.25f;
        }

        if (i > 0) {
            float* __restrict__ o = sOut + (i - 1) * 6;
            #pragma unroll
            for (int j = 0; j < 6; ++j)
                o[j] = 0.25f * (prev[j] + prev[j + 1] + cur[j] + cur[j + 1]);
        }
        #pragma unroll
        for (int j = 0; j < PH; ++j) prev[j] = cur[j];
    }

    __syncthreads();
    // coalesced store of the ROI's 9216 outputs
    float* __restrict__ orow = out + (size_t)roi * (C_CH * 36);
    #pragma unroll
    for (int e = t; e < C_CH * 36; e += 256) {
        const int cc = e / 36;
        const int kk = e - 36 * cc;
        orow[e] = s_out[cc * 37 + kk];
    }
}

// ---------------- fallback: direct fp32 gather (no workspace) ----------------
__global__ __launch_bounds__(256) void roialign_direct_kernel(
    const float* __restrict__ f0, const float* __restrict__ f1,
    const float* __restrict__ f2, const float* __restrict__ f3,
    const float* __restrict__ rois, float* __restrict__ out)
{
    const int roi = blockIdx.x;
    const int b   = roi / N_ROI;
    const float* r = rois + (size_t)roi * 7;

    __shared__ int   s_y0[14], s_y1[14], s_x0[14], s_x1[14];
    __shared__ float s_ly[14], s_lx[14], s_vy[14], s_vx[14];

    const int lev = (int)r[6];
    int H; const float* f;
    if      (lev == 0) { H = 160; f = f0; }
    else if (lev == 1) { H = 80;  f = f1; }
    else if (lev == 2) { H = 40;  f = f2; }
    else               { H = 20;  f = f3; }
    const int W = H;
    const float scale = (8.0f * (float)H) / (float)H0;
    const float x1 = r[1] * scale, y1 = r[2] * scale;
    const float x2 = r[3] * scale, y2 = r[4] * scale;
    const float bw = fmaxf(x2 - x1, 1.0f) * (1.0f / (float)PH);
    const float bh = fmaxf(y2 - y1, 1.0f) * (1.0f / (float)PH);

    const int t = threadIdx.x;
    if (t < 14) {
        const float off = (float)(t >> 1) + 0.25f + 0.5f * (float)(t & 1);
        const float ys  = y1 + off * bh;
        s_vy[t] = (ys >= -1.0f && ys <= (float)H) ? 1.0f : 0.0f;
        const float y  = fminf(fmaxf(ys, 0.0f), (float)(H - 1));
        const float yf = floorf(y);
        s_ly[t] = y - yf;
        const int y0 = (int)yf;
        s_y0[t] = y0 * W;
        s_y1[t] = min(y0 + 1, H - 1) * W;
    } else if (t < 28) {
        const int k = t - 14;
        const float off = (float)(k >> 1) + 0.25f + 0.5f * (float)(k & 1);
        const float xs  = x1 + off * bw;
        s_vx[k] = (xs >= -1.0f && xs <= (float)W) ? 1.0f : 0.0f;
        const float x  = fminf(fmaxf(xs, 0.0f), (float)(W - 1));
        const float xf = floorf(x);
        s_lx[k] = x - xf;
        const int x0 = (int)xf;
        s_x0[k] = x0;
        s_x1[k] = min(x0 + 1, W - 1);
    }
    __syncthreads();

    const int c = t;
    const float* __restrict__ fc = f + ((size_t)b * C_CH + c) * (size_t)(H * W);
    float* __restrict__ o_base = out + (size_t)roi * (C_CH * 36) + (size_t)c * 36;
    float prev[PH];

    for (int i = 0; i < PH; ++i) {
        const int   sy0 = 2 * i, sy1 = 2 * i + 1;
        const float lya = s_ly[sy0], vya = s_vy[sy0];
        const float lyb = s_ly[sy1], vyb = s_vy[sy1];
        const float* ra0 = fc + s_y0[sy0];
        const float* ra1 = fc + s_y1[sy0];
        const float* rb0 = fc + s_y0[sy1];
        const float* rb1 = fc + s_y1[sy1];
        float cur[PH];
        #pragma unroll
        for (int j = 0; j < PH; ++j) {
            float acc = 0.0f;
            #pragma unroll
            for (int sj = 0; sj < 2; ++sj) {
                const int   sx = 2 * j + sj;
                const int   x0 = s_x0[sx], x1i = s_x1[sx];
                const float lx = s_lx[sx], vx = s_vx[sx];
                {
                    const float f00 = ra0[x0], f01 = ra0[x1i];
                    const float f10 = ra1[x0], f11 = ra1[x1i];
                    const float top = f00 + lx * (f01 - f00);
                    const float bot = f10 + lx * (f11 - f10);
                    acc += (vya * vx) * (top + lya * (bot - top));
                }
                {
                    const float f00 = rb0[x0], f01 = rb0[x1i];
                    const float f10 = rb1[x0], f11 = rb1[x1i];
                    const float top = f00 + lx * (f01 - f00);
                    const float bot = f10 + lx * (f11 - f10);
                    acc += (vyb * vx) * (top + lyb * (bot - top));
                }
            }
            cur[j] = acc * 0.25f;
        }
        if (i > 0) {
            float* o = o_base + (size_t)(i - 1) * 6;
            #pragma unroll
            for (int j = 0; j < 6; ++j)
                o[j] = 0.25f * (prev[j] + prev[j + 1] + cur[j] + cur[j + 1]);
        }
        #pragma unroll
        for (int j = 0; j < PH; ++j) prev[j] = cur[j];
    }
}

extern "C" void kernel_launch(void* const* d_in, const int* in_sizes, int n_in,
                              void* d_out, int out_size, void* d_ws, size_t ws_size,
                              hipStream_t stream) {
    const float* f0   = (const float*)d_in[0];
    const float* f1   = (const float*)d_in[1];
    const float* f2   = (const float*)d_in[2];
    const float* f3   = (const float*)d_in[3];
    const float* rois = (const float*)d_in[4];
    float* out = (float*)d_out;

    const int n_rois = in_sizes[4] / 7;   // B*N = 1024
    const size_t need = WS_HALFS * sizeof(__half);

    if (d_ws != nullptr && ws_size >= need) {
        __half* ws = (__half*)d_ws;
        transpose_f16_kernel<<<NB_ALL, 256, 0, stream>>>(f0, f1, f2, f3, ws);
        roialign_kernel<<<n_rois, 256, 0, stream>>>(ws, rois, out);
    } else {
        roialign_direct_kernel<<<n_rois, 256, 0, stream>>>(f0, f1, f2, f3, rois, out);
    }
}

// Round 4
// 146.712 us; speedup vs baseline: 5.7139x; 1.1317x over previous
//
#include <hip/hip_runtime.h>
#include <hip/hip_bf16.h>
#include <hip/hip_fp16.h>

// RoIAlign (FPN, 4 levels) + SR=2x2 sample-mean + 2x2 stride-1 avg pool.
// B=2, N=512 rois, C=256, PH=PW=7, output (B*N, C*6*6) fp32.
//
// Round 4: gather uses __half2 channel-pair loads (half the load insts,
// double bytes/load), precomputed per-sample bilinear weights in LDS
// (fma_mix-shaped inner loop, no lerp chains), 2 thread-groups split bin
// rows. Transpose vectorized: float4 loads, half2 stores.

#define PH 7
#define C_CH 256
#define N_ROI 512
#define H0 160

// level sizes (P = H*W)
#define P0 25600
#define P1 6400
#define P2 1600
#define P3 400
// half-element offsets into ws for each transposed level (B=2, C=256)
#define OFF0 0ull
#define OFF1 (OFF0 + 2ull * C_CH * P0)
#define OFF2 (OFF1 + 2ull * C_CH * P1)
#define OFF3 (OFF2 + 2ull * C_CH * P2)
#define WS_HALFS (OFF3 + 2ull * C_CH * P3)   // 17,408,000 halves = 34.8 MB

// tile counts per level: ceil(P/64) * 4 (c-tiles) * 2 (batch)
#define NB0 (400 * 8)          // 3200
#define NB1 (100 * 8)          // 800
#define NB2 (25 * 8)           // 200
#define NB3 (7 * 8)            // 56  (last p-tile of P3 is partial)
#define NB_ALL (NB0 + NB1 + NB2 + NB3)

// ------------- fused (B,C,P) -> (B,P,C) transpose, fp32 -> fp16 -------------
__global__ __launch_bounds__(256) void transpose_f16_kernel(
    const float* __restrict__ f0, const float* __restrict__ f1,
    const float* __restrict__ f2, const float* __restrict__ f3,
    __half* __restrict__ ws)
{
    __shared__ float tile[64 * 65];
    int bid = blockIdx.x;
    const float* in; __half* outp; int P;
    if (bid < NB0)                  {              in = f0; outp = ws + OFF0; P = P0; }
    else if (bid < NB0 + NB1)       { bid -= NB0;  in = f1; outp = ws + OFF1; P = P1; }
    else if (bid < NB0 + NB1 + NB2) { bid -= NB0 + NB1; in = f2; outp = ws + OFF2; P = P2; }
    else                            { bid -= NB0 + NB1 + NB2; in = f3; outp = ws + OFF3; P = P3; }
    const int tiles_p = (P + 63) >> 6;
    const int tp   = bid % tiles_p;
    const int rest = bid / tiles_p;
    const int c0 = (rest & 3) << 6;
    const int b  = rest >> 2;
    const int p0 = tp << 6;
    const int pmax = P - p0;            // >=64 except last P3 tile (16)

    const int t = threadIdx.x;
    // phase 1: float4 loads along p, scalar LDS writes (row stride 65, <=2-way)
    const int pc  = (t & 15) << 2;      // 0,4,...,60
    const int cc0 = t >> 4;             // 0..15
    const float* A = in + ((size_t)b * C_CH + c0 + cc0) * (size_t)P + p0 + pc;
    if (pc < pmax) {
        #pragma unroll
        for (int k = 0; k < 4; ++k) {
            const float4 v = *(const float4*)(A + (size_t)(16 * k) * P);
            float* dst = tile + (cc0 + 16 * k) * 65 + pc;
            dst[0] = v.x; dst[1] = v.y; dst[2] = v.z; dst[3] = v.w;
        }
    }
    __syncthreads();
    // phase 2: pack channel pairs, half2 stores coalesced along c
    const int c2  = t & 31;             // channel pair within tile
    const int pr0 = t >> 5;             // 0..7
    __half2* O = (__half2*)outp + ((size_t)b * P + p0) * (C_CH / 2) + (c0 >> 1) + c2;
    #pragma unroll
    for (int k = 0; k < 8; ++k) {
        const int pp = pr0 + 8 * k;
        if (pp < pmax) {
            const float fx = tile[(2 * c2)     * 65 + pp];
            const float fy = tile[(2 * c2 + 1) * 65 + pp];
            O[(size_t)pp * (C_CH / 2)] = __floats2half2_rn(fx, fy);
        }
    }
}

// ---------------- main gather kernel (fp16 channels-last) ----------------
__global__ __launch_bounds__(256) void roialign_kernel(
    const __half* __restrict__ ws,
    const float* __restrict__ rois, float* __restrict__ out)
{
    const int roi = blockIdx.x;            // 0 .. B*N-1
    const int b   = roi / N_ROI;
    const float* r = rois + (size_t)roi * 7;

    __shared__ int    s_y0[14], s_y1[14], s_x0[14], s_x1[14];  // half2-unit offsets
    __shared__ float  s_ly[14], s_lx[14], s_vy[14], s_vx[14];
    __shared__ float4 s_w[14][14];         // [sy][sx] folded weights (x0.25, validity)
    __shared__ float  s_out[C_CH * 36];    // 40448 B total LDS -> 4 blocks/CU

    const int lev = (int)r[6];
    int H; const __half* ft;
    if      (lev == 0) { H = 160; ft = ws + OFF0; }
    else if (lev == 1) { H = 80;  ft = ws + OFF1; }
    else if (lev == 2) { H = 40;  ft = ws + OFF2; }
    else               { H = 20;  ft = ws + OFF3; }
    const int W = H;
    const int P = H * W;

    const float scale = (8.0f * (float)H) / (float)H0;
    const float x1 = r[1] * scale, y1 = r[2] * scale;
    const float x2 = r[3] * scale, y2 = r[4] * scale;
    const float bw = fmaxf(x2 - x1, 1.0f) * (1.0f / (float)PH);
    const float bh = fmaxf(y2 - y1, 1.0f) * (1.0f / (float)PH);

    const int t = threadIdx.x;
    if (t < 14) {
        const float off = (float)(t >> 1) + 0.25f + 0.5f * (float)(t & 1);
        const float ys  = y1 + off * bh;
        s_vy[t] = (ys >= -1.0f && ys <= (float)H) ? 1.0f : 0.0f;
        const float y  = fminf(fmaxf(ys, 0.0f), (float)(H - 1));
        const float yf = floorf(y);
        s_ly[t] = y - yf;
        const int y0 = (int)yf;
        s_y0[t] = y0 * (W * (C_CH / 2));
        s_y1[t] = min(y0 + 1, H - 1) * (W * (C_CH / 2));
    } else if (t < 28) {
        const int k = t - 14;
        const float off = (float)(k >> 1) + 0.25f + 0.5f * (float)(k & 1);
        const float xs  = x1 + off * bw;
        s_vx[k] = (xs >= -1.0f && xs <= (float)W) ? 1.0f : 0.0f;
        const float x  = fminf(fmaxf(xs, 0.0f), (float)(W - 1));
        const float xf = floorf(x);
        s_lx[k] = x - xf;
        const int x0 = (int)xf;
        s_x0[k] = x0 * (C_CH / 2);
        s_x1[k] = min(x0 + 1, W - 1) * (C_CH / 2);
    }
    __syncthreads();

    if (t < 196) {
        const int sy = t / 14, sx = t - 14 * sy;
        const float ly = s_ly[sy], lx = s_lx[sx];
        const float v  = 0.25f * s_vy[sy] * s_vx[sx];   // sample-mean folded
        const float hy = v * ly;
        const float my = v - hy;                         // v*(1-ly)
        s_w[sy][sx] = make_float4(my - my * lx, my * lx, hy - hy * lx, hy * lx);
    }
    __syncthreads();

    const int g  = t >> 7;                 // row group: 0 -> bins 0..3, 1 -> 3..6
    const int c2 = t & 127;                // channel pair (channels 2c2, 2c2+1)
    const __half2* __restrict__ cbase =
        (const __half2*)ft + (size_t)b * P * (C_CH / 2) + c2;

    const int i0 = g ? 3 : 0;
    const int i1 = g ? 7 : 4;
    float prevx[7], prevy[7];

    for (int i = i0; i < i1; ++i) {
        float curx[7], cury[7];
        #pragma unroll
        for (int j = 0; j < 7; ++j) { curx[j] = 0.0f; cury[j] = 0.0f; }

        #pragma unroll
        for (int syk = 0; syk < 2; ++syk) {
            const int sy = 2 * i + syk;
            const __half2* __restrict__ q0 = cbase + s_y0[sy];
            const __half2* __restrict__ q1 = cbase + s_y1[sy];
            #pragma unroll
            for (int j = 0; j < 7; ++j) {
                #pragma unroll
                for (int sxk = 0; sxk < 2; ++sxk) {
                    const int sx = 2 * j + sxk;
                    const float4 w = s_w[sy][sx];
                    const int xa = s_x0[sx], xb = s_x1[sx];
                    const __half2 h00 = q0[xa], h01 = q0[xb];
                    const __half2 h10 = q1[xa], h11 = q1[xb];
                    curx[j] += w.x * __low2float(h00)  + w.y * __low2float(h01)
                             + w.z * __low2float(h10)  + w.w * __low2float(h11);
                    cury[j] += w.x * __high2float(h00) + w.y * __high2float(h01)
                             + w.z * __high2float(h10) + w.w * __high2float(h11);
                }
            }
        }

        if (i > i0) {
            float* __restrict__ o0 = s_out + (2 * c2)     * 36 + (i - 1) * 6;
            float* __restrict__ o1 = s_out + (2 * c2 + 1) * 36 + (i - 1) * 6;
            #pragma unroll
            for (int j = 0; j < 6; ++j) {
                o0[j] = 0.25f * (prevx[j] + prevx[j + 1] + curx[j] + curx[j + 1]);
                o1[j] = 0.25f * (prevy[j] + prevy[j + 1] + cury[j] + cury[j + 1]);
            }
        }
        #pragma unroll
        for (int j = 0; j < 7; ++j) { prevx[j] = curx[j]; prevy[j] = cury[j]; }
    }

    __syncthreads();
    // coalesced store of the ROI's 9216 outputs
    float* __restrict__ orow = out + (size_t)roi * (C_CH * 36);
    #pragma unroll
    for (int e = t; e < C_CH * 36; e += 256)
        orow[e] = s_out[e];
}

// ---------------- fallback: direct fp32 gather (no workspace) ----------------
__global__ __launch_bounds__(256) void roialign_direct_kernel(
    const float* __restrict__ f0, const float* __restrict__ f1,
    const float* __restrict__ f2, const float* __restrict__ f3,
    const float* __restrict__ rois, float* __restrict__ out)
{
    const int roi = blockIdx.x;
    const int b   = roi / N_ROI;
    const float* r = rois + (size_t)roi * 7;

    __shared__ int   s_y0[14], s_y1[14], s_x0[14], s_x1[14];
    __shared__ float s_ly[14], s_lx[14], s_vy[14], s_vx[14];

    const int lev = (int)r[6];
    int H; const float* f;
    if      (lev == 0) { H = 160; f = f0; }
    else if (lev == 1) { H = 80;  f = f1; }
    else if (lev == 2) { H = 40;  f = f2; }
    else               { H = 20;  f = f3; }
    const int W = H;
    const float scale = (8.0f * (float)H) / (float)H0;
    const float x1 = r[1] * scale, y1 = r[2] * scale;
    const float x2 = r[3] * scale, y2 = r[4] * scale;
    const float bw = fmaxf(x2 - x1, 1.0f) * (1.0f / (float)PH);
    const float bh = fmaxf(y2 - y1, 1.0f) * (1.0f / (float)PH);

    const int t = threadIdx.x;
    if (t < 14) {
        const float off = (float)(t >> 1) + 0.25f + 0.5f * (float)(t & 1);
        const float ys  = y1 + off * bh;
        s_vy[t] = (ys >= -1.0f && ys <= (float)H) ? 1.0f : 0.0f;
        const float y  = fminf(fmaxf(ys, 0.0f), (float)(H - 1));
        const float yf = floorf(y);
        s_ly[t] = y - yf;
        const int y0 = (int)yf;
        s_y0[t] = y0 * W;
        s_y1[t] = min(y0 + 1, H - 1) * W;
    } else if (t < 28) {
        const int k = t - 14;
        const float off = (float)(k >> 1) + 0.25f + 0.5f * (float)(k & 1);
        const float xs  = x1 + off * bw;
        s_vx[k] = (xs >= -1.0f && xs <= (float)W) ? 1.0f : 0.0f;
        const float x  = fminf(fmaxf(xs, 0.0f), (float)(W - 1));
        const float xf = floorf(x);
        s_lx[k] = x - xf;
        const int x0 = (int)xf;
        s_x0[k] = x0;
        s_x1[k] = min(x0 + 1, W - 1);
    }
    __syncthreads();

    const int c = t;
    const float* __restrict__ fc = f + ((size_t)b * C_CH + c) * (size_t)(H * W);
    float* __restrict__ o_base = out + (size_t)roi * (C_CH * 36) + (size_t)c * 36;
    float prev[PH];

    for (int i = 0; i < PH; ++i) {
        const int   sy0 = 2 * i, sy1 = 2 * i + 1;
        const float lya = s_ly[sy0], vya = s_vy[sy0];
        const float lyb = s_ly[sy1], vyb = s_vy[sy1];
        const float* ra0 = fc + s_y0[sy0];
        const float* ra1 = fc + s_y1[sy0];
        const float* rb0 = fc + s_y0[sy1];
        const float* rb1 = fc + s_y1[sy1];
        float cur[PH];
        #pragma unroll
        for (int j = 0; j < PH; ++j) {
            float acc = 0.0f;
            #pragma unroll
            for (int sj = 0; sj < 2; ++sj) {
                const int   sx = 2 * j + sj;
                const int   x0 = s_x0[sx], x1i = s_x1[sx];
                const float lx = s_lx[sx], vx = s_vx[sx];
                {
                    const float f00 = ra0[x0], f01 = ra0[x1i];
                    const float f10 = ra1[x0], f11 = ra1[x1i];
                    const float top = f00 + lx * (f01 - f00);
                    const float bot = f10 + lx * (f11 - f10);
                    acc += (vya * vx) * (top + lya * (bot - top));
                }
                {
                    const float f00 = rb0[x0], f01 = rb0[x1i];
                    const float f10 = rb1[x0], f11 = rb1[x1i];
                    const float top = f00 + lx * (f01 - f00);
                    const float bot = f10 + lx * (f11 - f10);
                    acc += (vyb * vx) * (top + lyb * (bot - top));
                }
            }
            cur[j] = acc * 0.25f;
        }
        if (i > 0) {
            float* o = o_base + (size_t)(i - 1) * 6;
            #pragma unroll
            for (int j = 0; j < 6; ++j)
                o[j] = 0.25f * (prev[j] + prev[j + 1] + cur[j] + cur[j + 1]);
        }
        #pragma unroll
        for (int j = 0; j < PH; ++j) prev[j] = cur[j];
    }
}

extern "C" void kernel_launch(void* const* d_in, const int* in_sizes, int n_in,
                              void* d_out, int out_size, void* d_ws, size_t ws_size,
                              hipStream_t stream) {
    const float* f0   = (const float*)d_in[0];
    const float* f1   = (const float*)d_in[1];
    const float* f2   = (const float*)d_in[2];
    const float* f3   = (const float*)d_in[3];
    const float* rois = (const float*)d_in[4];
    float* out = (float*)d_out;

    const int n_rois = in_sizes[4] / 7;   // B*N = 1024
    const size_t need = WS_HALFS * sizeof(__half);

    if (d_ws != nullptr && ws_size >= need) {
        __half* ws = (__half*)d_ws;
        transpose_f16_kernel<<<NB_ALL, 256, 0, stream>>>(f0, f1, f2, f3, ws);
        roialign_kernel<<<n_rois, 256, 0, stream>>>(ws, rois, out);
    } else {
        roialign_direct_kernel<<<n_rois, 256, 0, stream>>>(f0, f1, f2, f3, rois, out);
    }
}